// Round 1
// 260.500 us; speedup vs baseline: 1.0085x; 1.0085x over previous
//
#include <hip/hip_runtime.h>
#include <stdint.h>

typedef unsigned short u16;
typedef __bf16 bf16_t;
typedef bf16_t bf16x8 __attribute__((ext_vector_type(8)));
typedef float f32x4 __attribute__((ext_vector_type(4)));
typedef u16 u16x4 __attribute__((ext_vector_type(4)));
typedef u16 u16x8 __attribute__((ext_vector_type(8)));

#define AS1 __attribute__((address_space(1)))
#define AS3 __attribute__((address_space(3)))

__device__ __forceinline__ u16 f2bf(float f) {
  union { float f; uint32_t u; } x; x.f = f;
  uint32_t u = x.u;
  return (u16)((u + 0x7fffu + ((u >> 16) & 1u)) >> 16);  // RNE
}

__device__ __forceinline__ void gload_lds16(const void* g, void* lds) {
  __builtin_amdgcn_global_load_lds((const AS1 uint32_t*)g, (AS3 uint32_t*)lds, 16, 0, 0);
}

// ---------------------------------------------------------------------------
// fp32 -> bf16 elementwise convert
// ---------------------------------------------------------------------------
__global__ __launch_bounds__(256) void cvt_bf16(const float* __restrict__ in,
                                                u16* __restrict__ out, int n4) {
  int i = blockIdx.x * 256 + threadIdx.x;
  if (i >= n4) return;
  float4 v = ((const float4*)in)[i];
  u16x4 o = {f2bf(v.x), f2bf(v.y), f2bf(v.z), f2bf(v.w)};
  *(u16x4*)(out + (size_t)i * 4) = o;
}

// ---------------------------------------------------------------------------
// 256x256 bf16 MFMA GEMM (C = A * B^T), 8-phase counted-vmcnt schedule
// (T3+T4+T5 per m201 template): BK=64, 8 waves (2Mx4N), 128KiB dbuf LDS,
// XOR-swizzled staging (T2). Each phase: {ds_read subtile || stage ONE
// half-tile (2 gload_lds/thread) -> barrier -> lgkmcnt(0) -> setprio(1) ->
// 16 MFMA -> setprio(0) -> barrier}. Stage stream runs 3 half-tiles ahead;
// tile boundaries wait vmcnt(6) (never 0 in steady state) so 3 half-tiles
// stay in flight across barriers. Half-death schedule (quadrant order
// (0,0),(1,0),(1,1),(0,1)): A0 dies p3, B0 p0, A1 p1, B1 p2 =>
// p0 stages A0(t+1) [buf 1-c], p1: B0(t+2), p2: A1(t+2), p3: B1(t+2)
// [all buf c, each one phase after that half's last read completed].
// A: [M][K] stride lda, B: [N][K] stride ldb, C: [M][N] stride ldc.
// z-batch via sAz/sBz/sCz. M=gridDim.y*256, N=gridDim.x*256, K%64==0, nt>=2.
// ---------------------------------------------------------------------------
#define BARRIER() do { asm volatile("" ::: "memory"); \
                       __builtin_amdgcn_s_barrier();  \
                       asm volatile("" ::: "memory"); } while (0)

#define MQ(MQi, NQi)                                                           \
  do {                                                                         \
    _Pragma("unroll") for (int j_ = 0; j_ < 4; ++j_) {                         \
      _Pragma("unroll") for (int i_ = 0; i_ < 2; ++i_) {                       \
        acc[(MQi) * 4 + j_][(NQi) * 2 + i_] =                                  \
            __builtin_amdgcn_mfma_f32_16x16x32_bf16(                           \
                Ar[j_][0], Br[i_][0], acc[(MQi) * 4 + j_][(NQi) * 2 + i_],     \
                0, 0, 0);                                                      \
        acc[(MQi) * 4 + j_][(NQi) * 2 + i_] =                                  \
            __builtin_amdgcn_mfma_f32_16x16x32_bf16(                           \
                Ar[j_][1], Br[i_][1], acc[(MQi) * 4 + j_][(NQi) * 2 + i_],     \
                0, 0, 0);                                                      \
      }                                                                        \
    }                                                                          \
  } while (0)

// one pipeline phase: all waves issue ds_reads+stage pre-barrier, then
// drain own lgkm, run the MFMA quadrant at high prio, re-align.
#define PHASE(MQi, NQi)                                                        \
  do {                                                                         \
    BARRIER();                                                                 \
    asm volatile("s_waitcnt lgkmcnt(0)" ::: "memory");                         \
    __builtin_amdgcn_sched_barrier(0);                                         \
    __builtin_amdgcn_s_setprio(1);                                             \
    MQ(MQi, NQi);                                                              \
    __builtin_amdgcn_s_setprio(0);                                             \
    BARRIER();                                                                 \
  } while (0)

template <bool BF16OUT>
__global__ __launch_bounds__(512, 2)
void gemm256(const u16* __restrict__ A, const u16* __restrict__ B,
             void* __restrict__ Cv,
             int lda, int ldb, int ldc,
             long long sAz, long long sBz, long long sCz,
             int K, float alpha) {
  __shared__ u16 As[2][256 * 64];   // 64 KiB
  __shared__ u16 Bs[2][256 * 64];   // 64 KiB
  const int tid  = threadIdx.x;
  const int lane = tid & 63;
  const int wid  = tid >> 6;        // 0..7
  const int wr   = wid >> 2;        // 0..1
  const int wc   = wid & 3;         // 0..3
  const long long z = blockIdx.z;
  const u16* Ab = A + z * sAz;
  const u16* Bb = B + z * sBz;
  const int rowBase = blockIdx.y * 256;
  const int colBase = blockIdx.x * 256;
  const int nt = K >> 6;

  // staging: thread t covers LDS linear chunk (row = h*128 + i*64 + t/8,
  // chunkpos = t&7); source chunk pre-swizzled with the reader's XOR
  // (rule 21: both-sides involution). Same 128B row segment -> coalesced.
  const int sRow   = tid >> 3;                    // 0..63
  const int sChunk = (tid & 7) ^ (sRow & 7);
  const size_t ldaS = (size_t)lda, ldbS = (size_t)ldb;
  const u16* aS = Ab + (size_t)(rowBase + sRow) * ldaS + sChunk * 8;
  const u16* bS = Bb + (size_t)(colBase + sRow) * ldbS + sChunk * 8;

  const int fr = lane & 15;   // fragment row within 16
  const int kx = lane >> 4;   // k-group 0..3
  const int rx = lane & 7;    // swizzle key (== frag row & 7)

  f32x4 acc[8][4];
  const f32x4 zf = {0.f, 0.f, 0.f, 0.f};
#pragma unroll
  for (int m = 0; m < 8; ++m)
#pragma unroll
    for (int n = 0; n < 4; ++n) acc[m][n] = zf;

  bf16x8 Ar[4][2], Br[2][2];

  // half-tile = one matrix, one 128-row half = 2 gload_lds per thread.
  auto stageA = [&](int buf, int h, int kt) {
    const u16* s = aS + (size_t)(h * 128) * ldaS + kt;
    char* d = ((char*)&As[buf][0]) + h * 16384 + tid * 16;
    gload_lds16(s, d);
    gload_lds16(s + 64 * ldaS, d + 8192);
  };
  auto stageB = [&](int buf, int h, int kt) {
    const u16* s = bS + (size_t)(h * 128) * ldbS + kt;
    char* d = ((char*)&Bs[buf][0]) + h * 16384 + tid * 16;
    gload_lds16(s, d);
    gload_lds16(s + 64 * ldbS, d + 8192);
  };
  auto ldsA = [&](int buf, int mq) {
#pragma unroll
    for (int j = 0; j < 4; ++j) {
      const int row = mq * 128 + wr * 64 + j * 16 + fr;
#pragma unroll
      for (int k = 0; k < 2; ++k) {
        const int ch = ((k * 4 + kx) ^ rx) * 8;
        Ar[j][k] = *(const bf16x8*)&As[buf][row * 64 + ch];
      }
    }
  };
  auto ldsB = [&](int buf, int nq) {
#pragma unroll
    for (int i = 0; i < 2; ++i) {
      const int row = nq * 128 + i * 64 + wc * 16 + fr;
#pragma unroll
      for (int k = 0; k < 2; ++k) {
        const int ch = ((k * 4 + kx) ^ rx) * 8;
        Br[i][k] = *(const bf16x8*)&Bs[buf][row * 64 + ch];
      }
    }
  };

  // prologue (nt>=2): tile0 all 4 halves -> buf0 (8 loads), then tile1's
  // B0,A1,B1 -> buf1 (6 loads; A0(1) is staged in loop t=0 phase 0).
  // vmcnt(6) => tile0's 8 loads landed, 3 half-tiles left in flight.
  stageA(0, 0, 0);
  stageB(0, 0, 0);
  stageA(0, 1, 0);
  stageB(0, 1, 0);
  stageB(1, 0, 64);
  stageA(1, 1, 64);
  stageB(1, 1, 64);
  asm volatile("s_waitcnt vmcnt(6)" ::: "memory");
  __builtin_amdgcn_sched_barrier(0);
  BARRIER();

  for (int t = 0; t < nt; ++t) {
    const int c = t & 1;
    const int kt1 = (t + 1) << 6;
    const int kt2 = (t + 2) << 6;
    const bool s1 = (t + 1 < nt);
    const bool s2 = (t + 2 < nt);
    // phase 0: read A0,B0(t); stage A0(t+1) into buf 1-c
    ldsA(c, 0); ldsB(c, 0);
    if (s1) stageA(1 - c, 0, kt1);
    PHASE(0, 0);
    // phase 1: read A1(t); stage B0(t+2) over B0(t) (dead since p0)
    ldsA(c, 1);
    if (s2) stageB(c, 0, kt2);
    PHASE(1, 0);
    // phase 2: read B1(t); stage A1(t+2) over A1(t) (dead since p1)
    ldsB(c, 1);
    if (s2) stageA(c, 1, kt2);
    PHASE(1, 1);
    // phase 3: re-read A0(t); stage B1(t+2) over B1(t) (dead since p2);
    // tile boundary: counted vmcnt so next tile's 4 halves are visible
    // while 3 half-tiles stay in flight.
    ldsA(c, 0);
    if (s2) stageB(c, 1, kt2);
    BARRIER();
    asm volatile("s_waitcnt lgkmcnt(0)" ::: "memory");
    __builtin_amdgcn_sched_barrier(0);
    __builtin_amdgcn_s_setprio(1);
    MQ(0, 1);
    __builtin_amdgcn_s_setprio(0);
    if (s1) {
      if (t == nt - 2) {
        asm volatile("s_waitcnt vmcnt(0)" ::: "memory");   // epilogue drain
      } else {
        asm volatile("s_waitcnt vmcnt(6)" ::: "memory");
      }
      __builtin_amdgcn_sched_barrier(0);
      BARRIER();
    }
  }

  // epilogue: C/D layout col=lane&15, row=(lane>>4)*4+reg [m89-verified]
  const int r0 = (lane >> 4) * 4;
#pragma unroll
  for (int m = 0; m < 8; ++m) {
    const int grow = rowBase + (m >> 2) * 128 + wr * 64 + (m & 3) * 16 + r0;
#pragma unroll
    for (int jj = 0; jj < 4; ++jj) {
      const size_t rOff = (size_t)(grow + jj) * (size_t)ldc;
      if constexpr (BF16OUT) {
        u16* C = (u16*)Cv + z * sCz;
#pragma unroll
        for (int n = 0; n < 4; ++n) {
          const int gcol = colBase + (n >> 1) * 128 + (n & 1) * 64 + wc * 16 + fr;
          C[rOff + gcol] = f2bf(acc[m][n][jj] * alpha);
        }
      } else {
        float* C = (float*)Cv + z * sCz;
#pragma unroll
        for (int n = 0; n < 4; ++n) {
          const int gcol = colBase + (n >> 1) * 128 + (n & 1) * 64 + wc * 16 + fr;
          C[rOff + gcol] = acc[m][n][jj] * alpha;
        }
      }
    }
  }
}

// ---------------------------------------------------------------------------
// v transpose: qkv[(t*4+b)*3072 + 2048 + e] -> vT[b][e][t]  (bf16)
// ---------------------------------------------------------------------------
__global__ __launch_bounds__(256)
void transpose_v(const u16* __restrict__ qkv, u16* __restrict__ vT) {
  __shared__ u16 tile[64][72];
  const int b  = blockIdx.z;
  const int t0 = blockIdx.x * 64;
  const int e0 = blockIdx.y * 64;
  const int tid = threadIdx.x;
  const int r  = tid >> 3;
  const int c8 = (tid & 7) * 8;
#pragma unroll
  for (int p = 0; p < 2; ++p) {
    const int t = t0 + p * 32 + r;
    const u16* src = qkv + (size_t)(t * 4 + b) * 3072 + 2048 + e0 + c8;
    *(u16x8*)&tile[p * 32 + r][c8] = *(const u16x8*)src;
  }
  __syncthreads();
#pragma unroll
  for (int p = 0; p < 2; ++p) {
    const int e = p * 32 + r;
    u16x8 v;
#pragma unroll
    for (int j = 0; j < 8; ++j) v[j] = tile[c8 + j][e];
    *(u16x8*)(vT + (size_t)b * 2097152 + (size_t)(e0 + e) * 2048 + t0 + c8) = v;
  }
}

// ---------------------------------------------------------------------------
// Row softmax over 2048 cols, in-place fp32 + bf16 copy.
// ---------------------------------------------------------------------------
__global__ __launch_bounds__(256)
void softmax_rows(float* __restrict__ sc, u16* __restrict__ wbf) {
  const size_t row = blockIdx.x;
  float* p = sc + row * 2048;
  const int tid = threadIdx.x;
  float4 v0 = ((const float4*)p)[tid * 2];
  float4 v1 = ((const float4*)p)[tid * 2 + 1];
  float x[8] = {v0.x, v0.y, v0.z, v0.w, v1.x, v1.y, v1.z, v1.w};
  float m = x[0];
#pragma unroll
  for (int j = 1; j < 8; ++j) m = fmaxf(m, x[j]);
#pragma unroll
  for (int o = 32; o; o >>= 1) m = fmaxf(m, __shfl_xor(m, o, 64));
  __shared__ float red[8];
  if ((tid & 63) == 0) red[tid >> 6] = m;
  __syncthreads();
  m = fmaxf(fmaxf(red[0], red[1]), fmaxf(red[2], red[3]));
  float e[8];
  float s = 0.f;
#pragma unroll
  for (int j = 0; j < 8; ++j) { e[j] = expf(x[j] - m); s += e[j]; }
#pragma unroll
  for (int o = 32; o; o >>= 1) s += __shfl_xor(s, o, 64);
  if ((tid & 63) == 0) red[4 + (tid >> 6)] = s;
  __syncthreads();
  s = (red[4] + red[5]) + (red[6] + red[7]);
  const float inv = 1.0f / s;
  float w[8];
#pragma unroll
  for (int j = 0; j < 8; ++j) w[j] = e[j] * inv;
  float4 o0 = {w[0], w[1], w[2], w[3]};
  float4 o1 = {w[4], w[5], w[6], w[7]};
  ((float4*)p)[tid * 2] = o0;
  ((float4*)p)[tid * 2 + 1] = o1;
  u16x8 ub;
#pragma unroll
  for (int j = 0; j < 8; ++j) ub[j] = f2bf(w[j]);
  *(u16x8*)(wbf + row * 2048 + tid * 8) = ub;
}

// ---------------------------------------------------------------------------
// S=2048, B=4, E=1024. inputs: Q, K(ignored), V(ignored), W_in, W_out (fp32)
// outputs: out [2048,4,1024] fp32 | weights [4,2048,2048] fp32
// ---------------------------------------------------------------------------
extern "C" void kernel_launch(void* const* d_in, const int* in_sizes, int n_in,
                              void* d_out, int out_size, void* d_ws, size_t ws_size,
                              hipStream_t stream) {
  const float* Q  = (const float*)d_in[0];
  const float* Wi = (const float*)d_in[3];
  const float* Wo = (const float*)d_in[4];
  float* out0    = (float*)d_out;
  float* weights = out0 + (size_t)2048 * 4 * 1024;  // 8388608

  char* ws = (char*)d_ws;
  u16* Qb   = (u16*)(ws);                          // 16 MiB [8192][1024]
  u16* Wib  = (u16*)(ws + ((size_t)16 << 20));     //  6 MiB [3072][1024]
  u16* Wob  = (u16*)(ws + ((size_t)22 << 20));     //  2 MiB [1024][1024]
  u16* qkvb = (u16*)(ws + ((size_t)24 << 20));     // 48 MiB [8192][3072]
  u16* vT   = (u16*)(ws + ((size_t)72 << 20));     // 16 MiB [4][1024][2048]
  u16* wbf  = (u16*)(ws + ((size_t)88 << 20));     // 32 MiB [4][2048][2048]
  u16* attb = Qb;  // alias: Qb dead after gemm1. [t][b][e] = [8192][1024]

  // 1) converts
  cvt_bf16<<<dim3(8192), dim3(256), 0, stream>>>(Q,  Qb,  2097152);
  cvt_bf16<<<dim3(3072), dim3(256), 0, stream>>>(Wi, Wib, 786432);
  cvt_bf16<<<dim3(1024), dim3(256), 0, stream>>>(Wo, Wob, 262144);

  // 2) qkv = Q * W_in^T : [8192,1024] x [3072,1024]^T -> bf16 [8192,3072]
  gemm256<true><<<dim3(12, 32, 1), dim3(512), 0, stream>>>(
      Qb, Wib, (void*)qkvb, 1024, 1024, 3072, 0, 0, 0, 1024, 1.0f);

  // 3) vT[b][e][t] from qkv v-part
  transpose_v<<<dim3(32, 16, 4), dim3(256), 0, stream>>>(qkvb, vT);

  // 4) scores[b] = (q/32) k^T -> fp32 into weights region of d_out
  gemm256<false><<<dim3(8, 8, 4), dim3(512), 0, stream>>>(
      qkvb, qkvb + 1024, (void*)weights, 12288, 12288, 2048,
      3072LL, 3072LL, 4194304LL, 1024, 0.03125f);

  // 5) softmax rows in place + bf16 copy
  softmax_rows<<<dim3(8192), dim3(256), 0, stream>>>(weights, wbf);

  // 6) att[t][b][e] = weights[b] * v[b]  (B = vT)
  gemm256<true><<<dim3(4, 8, 4), dim3(512), 0, stream>>>(
      wbf, vT, (void*)attb, 2048, 2048, 4096,
      4194304LL, 2097152LL, 1024LL, 2048, 1.0f);

  // 7) out = att * W_out^T -> fp32 d_out
  gemm256<false><<<dim3(4, 32, 1), dim3(512), 0, stream>>>(
      attb, Wob, (void*)out0, 1024, 1024, 1024, 0, 0, 0, 1024, 1.0f);
}

// Round 2
// 239.555 us; speedup vs baseline: 1.0967x; 1.0874x over previous
//
#include <hip/hip_runtime.h>
#include <stdint.h>

typedef unsigned short u16;
typedef __bf16 bf16_t;
typedef bf16_t bf16x8 __attribute__((ext_vector_type(8)));
typedef float f32x4 __attribute__((ext_vector_type(4)));
typedef u16 u16x4 __attribute__((ext_vector_type(4)));
typedef u16 u16x8 __attribute__((ext_vector_type(8)));

#define AS1 __attribute__((address_space(1)))
#define AS3 __attribute__((address_space(3)))

__device__ __forceinline__ u16 f2bf(float f) {
  union { float f; uint32_t u; } x; x.f = f;
  uint32_t u = x.u;
  return (u16)((u + 0x7fffu + ((u >> 16) & 1u)) >> 16);  // RNE
}

__device__ __forceinline__ void gload_lds16(const void* g, void* lds) {
  __builtin_amdgcn_global_load_lds((const AS1 uint32_t*)g, (AS3 uint32_t*)lds, 16, 0, 0);
}

// ---------------------------------------------------------------------------
// fp32 -> bf16 elementwise convert
// ---------------------------------------------------------------------------
__global__ __launch_bounds__(256) void cvt_bf16(const float* __restrict__ in,
                                                u16* __restrict__ out, int n4) {
  int i = blockIdx.x * 256 + threadIdx.x;
  if (i >= n4) return;
  float4 v = ((const float4*)in)[i];
  u16x4 o = {f2bf(v.x), f2bf(v.y), f2bf(v.z), f2bf(v.w)};
  *(u16x4*)(out + (size_t)i * 4) = o;
}

// ---------------------------------------------------------------------------
// 256x256 bf16 MFMA GEMM (C = A * B^T), register-double-buffered pipeline.
// Round-1 post-mortem: phase time 1406cyc == MFMA-issue 516 + LDS-drain 768,
// fully SERIAL, because each quadrant's ds_reads fill the same regs right
// before the consuming MFMA (per-quadrant lgkm drain; LDS FIFO re-syncs all
// waves each phase so cross-wave overlap never happens). Fix: 2 reg sets per
// operand (Ara/Arb, Bra/Brb); reads for quadrant q+1 issue BEFORE MFMA q, so
// each wave's LDS drain hides under its own 516-cyc MFMA burst. B0 persists
// in Bra all tile -> re-read eliminated (32->24 ds_read_b128/tile/wave).
// One barrier per tile; post-barrier reads (A0/B0 of t+1) are covered by the
// two deferred quadrants MQ(1,0)/MQ(1,1). Reg-set liveness invariant at tile
// entry: Ara=A0(t), Bra=B0(t); Arb/Brb dead.
// A: [M][K] stride lda, B: [N][K] stride ldb, C: [M][N] stride ldc.
// z-batch via sAz/sBz/sCz. M=gridDim.y*256, N=gridDim.x*256, K%64==0, nt>=2.
// ---------------------------------------------------------------------------
#define BARRIER() do { asm volatile("" ::: "memory"); \
                       __builtin_amdgcn_s_barrier();  \
                       asm volatile("" ::: "memory"); } while (0)

#define MQS(MQi, NQi, ASET, BSET)                                              \
  do {                                                                         \
    __builtin_amdgcn_s_setprio(1);                                             \
    _Pragma("unroll") for (int j_ = 0; j_ < 4; ++j_) {                         \
      _Pragma("unroll") for (int i_ = 0; i_ < 2; ++i_) {                       \
        acc[(MQi) * 4 + j_][(NQi) * 2 + i_] =                                  \
            __builtin_amdgcn_mfma_f32_16x16x32_bf16(                           \
                ASET[j_][0], BSET[i_][0],                                      \
                acc[(MQi) * 4 + j_][(NQi) * 2 + i_], 0, 0, 0);                 \
        acc[(MQi) * 4 + j_][(NQi) * 2 + i_] =                                  \
            __builtin_amdgcn_mfma_f32_16x16x32_bf16(                           \
                ASET[j_][1], BSET[i_][1],                                      \
                acc[(MQi) * 4 + j_][(NQi) * 2 + i_], 0, 0, 0);                 \
      }                                                                        \
    }                                                                          \
    __builtin_amdgcn_s_setprio(0);                                             \
  } while (0)

template <bool BF16OUT>
__global__ __launch_bounds__(512, 2)
void gemm256(const u16* __restrict__ A, const u16* __restrict__ B,
             void* __restrict__ Cv,
             int lda, int ldb, int ldc,
             long long sAz, long long sBz, long long sCz,
             int K, float alpha) {
  __shared__ u16 As[2][256 * 64];   // 64 KiB
  __shared__ u16 Bs[2][256 * 64];   // 64 KiB
  const int tid  = threadIdx.x;
  const int lane = tid & 63;
  const int wid  = tid >> 6;        // 0..7
  const int wr   = wid >> 2;        // 0..1
  const int wc   = wid & 3;         // 0..3
  const long long z = blockIdx.z;
  const u16* Ab = A + z * sAz;
  const u16* Bb = B + z * sBz;
  const int rowBase = blockIdx.y * 256;
  const int colBase = blockIdx.x * 256;
  const int nt = K >> 6;

  // staging: thread t covers LDS linear chunk (row = h*128 + i*64 + t/8,
  // chunkpos = t&7); source chunk pre-swizzled with the reader's XOR
  // (rule 21: both-sides involution). Same 128B row segment -> coalesced.
  const int sRow   = tid >> 3;                    // 0..63
  const int sChunk = (tid & 7) ^ (sRow & 7);
  const size_t ldaS = (size_t)lda, ldbS = (size_t)ldb;
  const u16* aS = Ab + (size_t)(rowBase + sRow) * ldaS + sChunk * 8;
  const u16* bS = Bb + (size_t)(colBase + sRow) * ldbS + sChunk * 8;

  const int fr = lane & 15;   // fragment row within 16
  const int kx = lane >> 4;   // k-group 0..3
  const int rx = lane & 7;    // swizzle key (== frag row & 7)

  f32x4 acc[8][4];
  const f32x4 zf = {0.f, 0.f, 0.f, 0.f};
#pragma unroll
  for (int m = 0; m < 8; ++m)
#pragma unroll
    for (int n = 0; n < 4; ++n) acc[m][n] = zf;

  // double-buffered operand fragment sets (static indexing only, rule #20)
  bf16x8 Ara[4][2], Arb[4][2], Bra[2][2], Brb[2][2];

  // half-tile = one matrix, one 128-row half = 2 gload_lds per thread.
  auto stageA = [&](int buf, int h, int kt) {
    const u16* s = aS + (size_t)(h * 128) * ldaS + kt;
    char* d = ((char*)&As[buf][0]) + h * 16384 + tid * 16;
    gload_lds16(s, d);
    gload_lds16(s + 64 * ldaS, d + 8192);
  };
  auto stageB = [&](int buf, int h, int kt) {
    const u16* s = bS + (size_t)(h * 128) * ldbS + kt;
    char* d = ((char*)&Bs[buf][0]) + h * 16384 + tid * 16;
    gload_lds16(s, d);
    gload_lds16(s + 64 * ldbS, d + 8192);
  };
  auto ldsA = [&](int buf, int mq, bf16x8 (&dst)[4][2]) {
#pragma unroll
    for (int j = 0; j < 4; ++j) {
      const int row = mq * 128 + wr * 64 + j * 16 + fr;
#pragma unroll
      for (int k = 0; k < 2; ++k) {
        const int ch = ((k * 4 + kx) ^ rx) * 8;
        dst[j][k] = *(const bf16x8*)&As[buf][row * 64 + ch];
      }
    }
  };
  auto ldsB = [&](int buf, int nq, bf16x8 (&dst)[2][2]) {
#pragma unroll
    for (int i = 0; i < 2; ++i) {
      const int row = nq * 128 + i * 64 + wc * 16 + fr;
#pragma unroll
      for (int k = 0; k < 2; ++k) {
        const int ch = ((k * 4 + kx) ^ rx) * 8;
        dst[i][k] = *(const bf16x8*)&Bs[buf][row * 64 + ch];
      }
    }
  };

  // prologue: tile0 all 4 halves -> buf0; then first operand sets.
  stageA(0, 0, 0);
  stageA(0, 1, 0);
  stageB(0, 0, 0);
  stageB(0, 1, 0);
  asm volatile("s_waitcnt vmcnt(0)" ::: "memory");
  BARRIER();
  ldsA(0, 0, Ara);              // A0(0)
  ldsB(0, 0, Bra);              // B0(0)

  for (int t = 0; t < nt; ++t) {
    const int c = t & 1;
    const int kt1 = (t + 1) << 6;
    const bool s1 = (t + 1 < nt);
    // pre-barrier: issue ALL of this tile's remaining reads first (their
    // lgkm drain hides under MQ(0,0)+MQ(0,1)), then next tile's staging.
    ldsB(c, 1, Brb);            // B1(t), 4 reads; consumer MQ(0,1)
    ldsA(c, 1, Arb);            // A1(t), 8 reads; consumer MQ(1,0) post-bar
    if (s1) {
      stageA(1 - c, 0, kt1);    // 8 gloads: all 4 halves of tile t+1
      stageA(1 - c, 1, kt1);
      stageB(1 - c, 0, kt1);
      stageB(1 - c, 1, kt1);
    }
    MQS(0, 0, Ara, Bra);
    MQS(0, 1, Ara, Brb);
    if (s1) {
      // race fence: A1(t)/B1(t) reads must be SERVED before any wave's
      // post-barrier staging of tile t+2 can overwrite them next iter;
      // ~free (issued 2 MFMA bursts ago). Then buffer-flip handshake.
      asm volatile("s_waitcnt lgkmcnt(0)" ::: "memory");
      asm volatile("s_waitcnt vmcnt(0)" ::: "memory");
      BARRIER();
      ldsA(1 - c, 0, Ara);      // A0(t+1), 8 reads; drains under MQ(1,0)
      __builtin_amdgcn_sched_barrier(0);
    }
    MQS(1, 0, Arb, Bra);        // last use of Bra=B0(t)
    if (s1) ldsB(1 - c, 0, Bra);// B0(t+1), 4 reads; drains under MQ(1,1)
    MQS(1, 1, Arb, Brb);
    // invariant restored: Ara=A0(t+1), Bra=B0(t+1)
  }

  // epilogue: C/D layout col=lane&15, row=(lane>>4)*4+reg [m89-verified]
  const int r0 = (lane >> 4) * 4;
#pragma unroll
  for (int m = 0; m < 8; ++m) {
    const int grow = rowBase + (m >> 2) * 128 + wr * 64 + (m & 3) * 16 + r0;
#pragma unroll
    for (int jj = 0; jj < 4; ++jj) {
      const size_t rOff = (size_t)(grow + jj) * (size_t)ldc;
      if constexpr (BF16OUT) {
        u16* C = (u16*)Cv + z * sCz;
#pragma unroll
        for (int n = 0; n < 4; ++n) {
          const int gcol = colBase + (n >> 1) * 128 + (n & 1) * 64 + wc * 16 + fr;
          C[rOff + gcol] = f2bf(acc[m][n][jj] * alpha);
        }
      } else {
        float* C = (float*)Cv + z * sCz;
#pragma unroll
        for (int n = 0; n < 4; ++n) {
          const int gcol = colBase + (n >> 1) * 128 + (n & 1) * 64 + wc * 16 + fr;
          C[rOff + gcol] = acc[m][n][jj] * alpha;
        }
      }
    }
  }
}

// ---------------------------------------------------------------------------
// v transpose: qkv[(t*4+b)*3072 + 2048 + e] -> vT[b][e][t]  (bf16)
// ---------------------------------------------------------------------------
__global__ __launch_bounds__(256)
void transpose_v(const u16* __restrict__ qkv, u16* __restrict__ vT) {
  __shared__ u16 tile[64][72];
  const int b  = blockIdx.z;
  const int t0 = blockIdx.x * 64;
  const int e0 = blockIdx.y * 64;
  const int tid = threadIdx.x;
  const int r  = tid >> 3;
  const int c8 = (tid & 7) * 8;
#pragma unroll
  for (int p = 0; p < 2; ++p) {
    const int t = t0 + p * 32 + r;
    const u16* src = qkv + (size_t)(t * 4 + b) * 3072 + 2048 + e0 + c8;
    *(u16x8*)&tile[p * 32 + r][c8] = *(const u16x8*)src;
  }
  __syncthreads();
#pragma unroll
  for (int p = 0; p < 2; ++p) {
    const int e = p * 32 + r;
    u16x8 v;
#pragma unroll
    for (int j = 0; j < 8; ++j) v[j] = tile[c8 + j][e];
    *(u16x8*)(vT + (size_t)b * 2097152 + (size_t)(e0 + e) * 2048 + t0 + c8) = v;
  }
}

// ---------------------------------------------------------------------------
// Row softmax over 2048 cols, in-place fp32 + bf16 copy.
// ---------------------------------------------------------------------------
__global__ __launch_bounds__(256)
void softmax_rows(float* __restrict__ sc, u16* __restrict__ wbf) {
  const size_t row = blockIdx.x;
  float* p = sc + row * 2048;
  const int tid = threadIdx.x;
  float4 v0 = ((const float4*)p)[tid * 2];
  float4 v1 = ((const float4*)p)[tid * 2 + 1];
  float x[8] = {v0.x, v0.y, v0.z, v0.w, v1.x, v1.y, v1.z, v1.w};
  float m = x[0];
#pragma unroll
  for (int j = 1; j < 8; ++j) m = fmaxf(m, x[j]);
#pragma unroll
  for (int o = 32; o; o >>= 1) m = fmaxf(m, __shfl_xor(m, o, 64));
  __shared__ float red[8];
  if ((tid & 63) == 0) red[tid >> 6] = m;
  __syncthreads();
  m = fmaxf(fmaxf(red[0], red[1]), fmaxf(red[2], red[3]));
  float e[8];
  float s = 0.f;
#pragma unroll
  for (int j = 0; j < 8; ++j) { e[j] = expf(x[j] - m); s += e[j]; }
#pragma unroll
  for (int o = 32; o; o >>= 1) s += __shfl_xor(s, o, 64);
  if ((tid & 63) == 0) red[4 + (tid >> 6)] = s;
  __syncthreads();
  s = (red[4] + red[5]) + (red[6] + red[7]);
  const float inv = 1.0f / s;
  float w[8];
#pragma unroll
  for (int j = 0; j < 8; ++j) w[j] = e[j] * inv;
  float4 o0 = {w[0], w[1], w[2], w[3]};
  float4 o1 = {w[4], w[5], w[6], w[7]};
  ((float4*)p)[tid * 2] = o0;
  ((float4*)p)[tid * 2 + 1] = o1;
  u16x8 ub;
#pragma unroll
  for (int j = 0; j < 8; ++j) ub[j] = f2bf(w[j]);
  *(u16x8*)(wbf + row * 2048 + tid * 8) = ub;
}

// ---------------------------------------------------------------------------
// S=2048, B=4, E=1024. inputs: Q, K(ignored), V(ignored), W_in, W_out (fp32)
// outputs: out [2048,4,1024] fp32 | weights [4,2048,2048] fp32
// ---------------------------------------------------------------------------
extern "C" void kernel_launch(void* const* d_in, const int* in_sizes, int n_in,
                              void* d_out, int out_size, void* d_ws, size_t ws_size,
                              hipStream_t stream) {
  const float* Q  = (const float*)d_in[0];
  const float* Wi = (const float*)d_in[3];
  const float* Wo = (const float*)d_in[4];
  float* out0    = (float*)d_out;
  float* weights = out0 + (size_t)2048 * 4 * 1024;  // 8388608

  char* ws = (char*)d_ws;
  u16* Qb   = (u16*)(ws);                          // 16 MiB [8192][1024]
  u16* Wib  = (u16*)(ws + ((size_t)16 << 20));     //  6 MiB [3072][1024]
  u16* Wob  = (u16*)(ws + ((size_t)22 << 20));     //  2 MiB [1024][1024]
  u16* qkvb = (u16*)(ws + ((size_t)24 << 20));     // 48 MiB [8192][3072]
  u16* vT   = (u16*)(ws + ((size_t)72 << 20));     // 16 MiB [4][1024][2048]
  u16* wbf  = (u16*)(ws + ((size_t)88 << 20));     // 32 MiB [4][2048][2048]
  u16* attb = Qb;  // alias: Qb dead after gemm1. [t][b][e] = [8192][1024]

  // 1) converts
  cvt_bf16<<<dim3(8192), dim3(256), 0, stream>>>(Q,  Qb,  2097152);
  cvt_bf16<<<dim3(3072), dim3(256), 0, stream>>>(Wi, Wib, 786432);
  cvt_bf16<<<dim3(1024), dim3(256), 0, stream>>>(Wo, Wob, 262144);

  // 2) qkv = Q * W_in^T : [8192,1024] x [3072,1024]^T -> bf16 [8192,3072]
  gemm256<true><<<dim3(12, 32, 1), dim3(512), 0, stream>>>(
      Qb, Wib, (void*)qkvb, 1024, 1024, 3072, 0, 0, 0, 1024, 1.0f);

  // 3) vT[b][e][t] from qkv v-part
  transpose_v<<<dim3(32, 16, 4), dim3(256), 0, stream>>>(qkvb, vT);

  // 4) scores[b] = (q/32) k^T -> fp32 into weights region of d_out
  gemm256<false><<<dim3(8, 8, 4), dim3(512), 0, stream>>>(
      qkvb, qkvb + 1024, (void*)weights, 12288, 12288, 2048,
      3072LL, 3072LL, 4194304LL, 1024, 0.03125f);

  // 5) softmax rows in place + bf16 copy
  softmax_rows<<<dim3(8192), dim3(256), 0, stream>>>(weights, wbf);

  // 6) att[t][b][e] = weights[b] * v[b]  (B = vT)
  gemm256<true><<<dim3(4, 8, 4), dim3(512), 0, stream>>>(
      wbf, vT, (void*)attb, 2048, 2048, 4096,
      4194304LL, 2097152LL, 1024LL, 2048, 1.0f);

  // 7) out = att * W_out^T -> fp32 d_out
  gemm256<false><<<dim3(4, 32, 1), dim3(512), 0, stream>>>(
      attb, Wob, (void*)out0, 1024, 1024, 1024, 0, 0, 0, 1024, 1.0f);
}

// Round 3
// 230.567 us; speedup vs baseline: 1.1395x; 1.0390x over previous
//
#include <hip/hip_runtime.h>
#include <stdint.h>

typedef unsigned short u16;
typedef __bf16 bf16_t;
typedef bf16_t bf16x8 __attribute__((ext_vector_type(8)));
typedef float f32x4 __attribute__((ext_vector_type(4)));
typedef u16 u16x4 __attribute__((ext_vector_type(4)));
typedef u16 u16x8 __attribute__((ext_vector_type(8)));

#define AS1 __attribute__((address_space(1)))
#define AS3 __attribute__((address_space(3)))

__device__ __forceinline__ u16 f2bf(float f) {
  union { float f; uint32_t u; } x; x.f = f;
  uint32_t u = x.u;
  return (u16)((u + 0x7fffu + ((u >> 16) & 1u)) >> 16);  // RNE
}

__device__ __forceinline__ float bf2f(u16 b) {
  union { uint32_t u; float f; } x; x.u = ((uint32_t)b) << 16;
  return x.f;
}

__device__ __forceinline__ void gload_lds16(const void* g, void* lds) {
  __builtin_amdgcn_global_load_lds((const AS1 uint32_t*)g, (AS3 uint32_t*)lds, 16, 0, 0);
}

// ---------------------------------------------------------------------------
// fp32 -> bf16 elementwise convert
// ---------------------------------------------------------------------------
__global__ __launch_bounds__(256) void cvt_bf16(const float* __restrict__ in,
                                                u16* __restrict__ out, int n4) {
  int i = blockIdx.x * 256 + threadIdx.x;
  if (i >= n4) return;
  float4 v = ((const float4*)in)[i];
  u16x4 o = {f2bf(v.x), f2bf(v.y), f2bf(v.z), f2bf(v.w)};
  *(u16x4*)(out + (size_t)i * 4) = o;
}

// ---------------------------------------------------------------------------
// 256x256 bf16 MFMA GEMM (C = A * B^T), register-double-buffered pipeline
// (round-2 winner, unchanged core). 2 reg sets per operand (Ara/Arb,
// Bra/Brb); reads for quadrant q+1 issue BEFORE MFMA q so each wave's LDS
// drain hides under its own MFMA burst. B0 persists in Bra all tile.
// Occupancy note (round-2 counters): 128 VGPR + 128 acc-AGPR ~= 256 unified
// -> 2 waves/SIMD, 1 block/CU; this is register-pinned, not LDS-pinned.
// A: [M][K] stride lda, B: [N][K] stride ldb, C: [M][N] stride ldc.
// z-batch via sAz/sBz/sCz. M=gridDim.y*256, N=gridDim.x*256, K%64==0, nt>=2.
// ---------------------------------------------------------------------------
#define BARRIER() do { asm volatile("" ::: "memory"); \
                       __builtin_amdgcn_s_barrier();  \
                       asm volatile("" ::: "memory"); } while (0)

#define MQS(MQi, NQi, ASET, BSET)                                              \
  do {                                                                         \
    __builtin_amdgcn_s_setprio(1);                                             \
    _Pragma("unroll") for (int j_ = 0; j_ < 4; ++j_) {                         \
      _Pragma("unroll") for (int i_ = 0; i_ < 2; ++i_) {                       \
        acc[(MQi) * 4 + j_][(NQi) * 2 + i_] =                                  \
            __builtin_amdgcn_mfma_f32_16x16x32_bf16(                           \
                ASET[j_][0], BSET[i_][0],                                      \
                acc[(MQi) * 4 + j_][(NQi) * 2 + i_], 0, 0, 0);                 \
        acc[(MQi) * 4 + j_][(NQi) * 2 + i_] =                                  \
            __builtin_amdgcn_mfma_f32_16x16x32_bf16(                           \
                ASET[j_][1], BSET[i_][1],                                      \
                acc[(MQi) * 4 + j_][(NQi) * 2 + i_], 0, 0, 0);                 \
      }                                                                        \
    }                                                                          \
    __builtin_amdgcn_s_setprio(0);                                             \
  } while (0)

template <bool BF16OUT>
__global__ __launch_bounds__(512, 2)
void gemm256(const u16* __restrict__ A, const u16* __restrict__ B,
             void* __restrict__ Cv,
             int lda, int ldb, int ldc,
             long long sAz, long long sBz, long long sCz,
             int K, float alpha) {
  __shared__ u16 As[2][256 * 64];   // 64 KiB
  __shared__ u16 Bs[2][256 * 64];   // 64 KiB
  const int tid  = threadIdx.x;
  const int lane = tid & 63;
  const int wid  = tid >> 6;        // 0..7
  const int wr   = wid >> 2;        // 0..1
  const int wc   = wid & 3;         // 0..3
  const long long z = blockIdx.z;
  const u16* Ab = A + z * sAz;
  const u16* Bb = B + z * sBz;
  const int rowBase = blockIdx.y * 256;
  const int colBase = blockIdx.x * 256;
  const int nt = K >> 6;

  // staging: thread t covers LDS linear chunk (row = h*128 + i*64 + t/8,
  // chunkpos = t&7); source chunk pre-swizzled with the reader's XOR
  // (rule 21: both-sides involution). Same 128B row segment -> coalesced.
  const int sRow   = tid >> 3;                    // 0..63
  const int sChunk = (tid & 7) ^ (sRow & 7);
  const size_t ldaS = (size_t)lda, ldbS = (size_t)ldb;
  const u16* aS = Ab + (size_t)(rowBase + sRow) * ldaS + sChunk * 8;
  const u16* bS = Bb + (size_t)(colBase + sRow) * ldbS + sChunk * 8;

  const int fr = lane & 15;   // fragment row within 16
  const int kx = lane >> 4;   // k-group 0..3
  const int rx = lane & 7;    // swizzle key (== frag row & 7)

  f32x4 acc[8][4];
  const f32x4 zf = {0.f, 0.f, 0.f, 0.f};
#pragma unroll
  for (int m = 0; m < 8; ++m)
#pragma unroll
    for (int n = 0; n < 4; ++n) acc[m][n] = zf;

  // double-buffered operand fragment sets (static indexing only, rule #20)
  bf16x8 Ara[4][2], Arb[4][2], Bra[2][2], Brb[2][2];

  // half-tile = one matrix, one 128-row half = 2 gload_lds per thread.
  auto stageA = [&](int buf, int h, int kt) {
    const u16* s = aS + (size_t)(h * 128) * ldaS + kt;
    char* d = ((char*)&As[buf][0]) + h * 16384 + tid * 16;
    gload_lds16(s, d);
    gload_lds16(s + 64 * ldaS, d + 8192);
  };
  auto stageB = [&](int buf, int h, int kt) {
    const u16* s = bS + (size_t)(h * 128) * ldbS + kt;
    char* d = ((char*)&Bs[buf][0]) + h * 16384 + tid * 16;
    gload_lds16(s, d);
    gload_lds16(s + 64 * ldbS, d + 8192);
  };
  auto ldsA = [&](int buf, int mq, bf16x8 (&dst)[4][2]) {
#pragma unroll
    for (int j = 0; j < 4; ++j) {
      const int row = mq * 128 + wr * 64 + j * 16 + fr;
#pragma unroll
      for (int k = 0; k < 2; ++k) {
        const int ch = ((k * 4 + kx) ^ rx) * 8;
        dst[j][k] = *(const bf16x8*)&As[buf][row * 64 + ch];
      }
    }
  };
  auto ldsB = [&](int buf, int nq, bf16x8 (&dst)[2][2]) {
#pragma unroll
    for (int i = 0; i < 2; ++i) {
      const int row = nq * 128 + i * 64 + wc * 16 + fr;
#pragma unroll
      for (int k = 0; k < 2; ++k) {
        const int ch = ((k * 4 + kx) ^ rx) * 8;
        dst[i][k] = *(const bf16x8*)&Bs[buf][row * 64 + ch];
      }
    }
  };

  // prologue: tile0 all 4 halves -> buf0; then first operand sets.
  stageA(0, 0, 0);
  stageA(0, 1, 0);
  stageB(0, 0, 0);
  stageB(0, 1, 0);
  asm volatile("s_waitcnt vmcnt(0)" ::: "memory");
  BARRIER();
  ldsA(0, 0, Ara);              // A0(0)
  ldsB(0, 0, Bra);              // B0(0)

  for (int t = 0; t < nt; ++t) {
    const int c = t & 1;
    const int kt1 = (t + 1) << 6;
    const bool s1 = (t + 1 < nt);
    // pre-barrier: issue ALL of this tile's remaining reads first (their
    // lgkm drain hides under MQ(0,0)+MQ(0,1)), then next tile's staging.
    ldsB(c, 1, Brb);            // B1(t), 4 reads; consumer MQ(0,1)
    ldsA(c, 1, Arb);            // A1(t), 8 reads; consumer MQ(1,0) post-bar
    if (s1) {
      stageA(1 - c, 0, kt1);    // 8 gloads: all 4 halves of tile t+1
      stageA(1 - c, 1, kt1);
      stageB(1 - c, 0, kt1);
      stageB(1 - c, 1, kt1);
    }
    MQS(0, 0, Ara, Bra);
    MQS(0, 1, Ara, Brb);
    if (s1) {
      // race fence: A1(t)/B1(t) reads must be SERVED before any wave's
      // post-barrier staging of tile t+2 can overwrite them next iter;
      // ~free (issued 2 MFMA bursts ago). Then buffer-flip handshake.
      asm volatile("s_waitcnt lgkmcnt(0)" ::: "memory");
      asm volatile("s_waitcnt vmcnt(0)" ::: "memory");
      BARRIER();
      ldsA(1 - c, 0, Ara);      // A0(t+1), 8 reads; drains under MQ(1,0)
      __builtin_amdgcn_sched_barrier(0);
    }
    MQS(1, 0, Arb, Bra);        // last use of Bra=B0(t)
    if (s1) ldsB(1 - c, 0, Bra);// B0(t+1), 4 reads; drains under MQ(1,1)
    MQS(1, 1, Arb, Brb);
    // invariant restored: Ara=A0(t+1), Bra=B0(t+1)
  }

  // epilogue: C/D layout col=lane&15, row=(lane>>4)*4+reg [m89-verified]
  const int r0 = (lane >> 4) * 4;
#pragma unroll
  for (int m = 0; m < 8; ++m) {
    const int grow = rowBase + (m >> 2) * 128 + wr * 64 + (m & 3) * 16 + r0;
#pragma unroll
    for (int jj = 0; jj < 4; ++jj) {
      const size_t rOff = (size_t)(grow + jj) * (size_t)ldc;
      if constexpr (BF16OUT) {
        u16* C = (u16*)Cv + z * sCz;
#pragma unroll
        for (int n = 0; n < 4; ++n) {
          const int gcol = colBase + (n >> 1) * 128 + (n & 1) * 64 + wc * 16 + fr;
          C[rOff + gcol] = f2bf(acc[m][n][jj] * alpha);
        }
      } else {
        float* C = (float*)Cv + z * sCz;
#pragma unroll
        for (int n = 0; n < 4; ++n) {
          const int gcol = colBase + (n >> 1) * 128 + (n & 1) * 64 + wc * 16 + fr;
          C[rOff + gcol] = acc[m][n][jj] * alpha;
        }
      }
    }
  }
}

// ---------------------------------------------------------------------------
// v transpose: qkv[(t*4+b)*3072 + 2048 + e] -> vT[b][e][t]  (bf16)
// ---------------------------------------------------------------------------
__global__ __launch_bounds__(256)
void transpose_v(const u16* __restrict__ qkv, u16* __restrict__ vT) {
  __shared__ u16 tile[64][72];
  const int b  = blockIdx.z;
  const int t0 = blockIdx.x * 64;
  const int e0 = blockIdx.y * 64;
  const int tid = threadIdx.x;
  const int r  = tid >> 3;
  const int c8 = (tid & 7) * 8;
#pragma unroll
  for (int p = 0; p < 2; ++p) {
    const int t = t0 + p * 32 + r;
    const u16* src = qkv + (size_t)(t * 4 + b) * 3072 + 2048 + e0 + c8;
    *(u16x8*)&tile[p * 32 + r][c8] = *(const u16x8*)src;
  }
  __syncthreads();
#pragma unroll
  for (int p = 0; p < 2; ++p) {
    const int e = p * 32 + r;
    u16x8 v;
#pragma unroll
    for (int j = 0; j < 8; ++j) v[j] = tile[c8 + j][e];
    *(u16x8*)(vT + (size_t)b * 2097152 + (size_t)(e0 + e) * 2048 + t0 + c8) = v;
  }
}

// ---------------------------------------------------------------------------
// Row softmax over 2048 cols: reads bf16 scores (already scaled by 1/32),
// writes fp32 weights (required output) + bf16 probs IN PLACE over scores.
// Chain traffic: 32 MB read + 128 MB + 32 MB write (was 128+128+32+...).
// ---------------------------------------------------------------------------
__global__ __launch_bounds__(256)
void softmax_rows(u16* __restrict__ sbf, float* __restrict__ wfp) {
  const size_t row = blockIdx.x;
  const int tid = threadIdx.x;
  u16* pb = sbf + row * 2048;
  u16x8 xb = *(const u16x8*)(pb + tid * 8);
  float x[8];
#pragma unroll
  for (int j = 0; j < 8; ++j) x[j] = bf2f(xb[j]);
  float m = x[0];
#pragma unroll
  for (int j = 1; j < 8; ++j) m = fmaxf(m, x[j]);
#pragma unroll
  for (int o = 32; o; o >>= 1) m = fmaxf(m, __shfl_xor(m, o, 64));
  __shared__ float red[8];
  if ((tid & 63) == 0) red[tid >> 6] = m;
  __syncthreads();
  m = fmaxf(fmaxf(red[0], red[1]), fmaxf(red[2], red[3]));
  float e[8];
  float s = 0.f;
#pragma unroll
  for (int j = 0; j < 8; ++j) { e[j] = expf(x[j] - m); s += e[j]; }
#pragma unroll
  for (int o = 32; o; o >>= 1) s += __shfl_xor(s, o, 64);
  if ((tid & 63) == 0) red[4 + (tid >> 6)] = s;
  __syncthreads();
  s = (red[4] + red[5]) + (red[6] + red[7]);
  const float inv = 1.0f / s;
  float w[8];
#pragma unroll
  for (int j = 0; j < 8; ++j) w[j] = e[j] * inv;
  float* pf = wfp + row * 2048;
  float4 o0 = {w[0], w[1], w[2], w[3]};
  float4 o1 = {w[4], w[5], w[6], w[7]};
  ((float4*)pf)[tid * 2] = o0;
  ((float4*)pf)[tid * 2 + 1] = o1;
  u16x8 ub;
#pragma unroll
  for (int j = 0; j < 8; ++j) ub[j] = f2bf(w[j]);
  *(u16x8*)(pb + tid * 8) = ub;
}

// ---------------------------------------------------------------------------
// S=2048, B=4, E=1024. inputs: Q, K(ignored), V(ignored), W_in, W_out (fp32)
// outputs: out [2048,4,1024] fp32 | weights [4,2048,2048] fp32
// ---------------------------------------------------------------------------
extern "C" void kernel_launch(void* const* d_in, const int* in_sizes, int n_in,
                              void* d_out, int out_size, void* d_ws, size_t ws_size,
                              hipStream_t stream) {
  const float* Q  = (const float*)d_in[0];
  const float* Wi = (const float*)d_in[3];
  const float* Wo = (const float*)d_in[4];
  float* out0    = (float*)d_out;
  float* weights = out0 + (size_t)2048 * 4 * 1024;  // 8388608

  char* ws = (char*)d_ws;
  u16* Qb   = (u16*)(ws);                          // 16 MiB [8192][1024]
  u16* Wib  = (u16*)(ws + ((size_t)16 << 20));     //  6 MiB [3072][1024]
  u16* Wob  = (u16*)(ws + ((size_t)22 << 20));     //  2 MiB [1024][1024]
  u16* qkvb = (u16*)(ws + ((size_t)24 << 20));     // 48 MiB [8192][3072]
  u16* vT   = (u16*)(ws + ((size_t)72 << 20));     // 16 MiB [4][1024][2048]
  u16* wbf  = (u16*)(ws + ((size_t)88 << 20));     // 32 MiB [4][2048][2048]
  u16* attb = Qb;  // alias: Qb dead after gemm1. [t][b][e] = [8192][1024]

  // 1) converts
  cvt_bf16<<<dim3(8192), dim3(256), 0, stream>>>(Q,  Qb,  2097152);
  cvt_bf16<<<dim3(3072), dim3(256), 0, stream>>>(Wi, Wib, 786432);
  cvt_bf16<<<dim3(1024), dim3(256), 0, stream>>>(Wo, Wob, 262144);

  // 2) qkv = Q * W_in^T : [8192,1024] x [3072,1024]^T -> bf16 [8192,3072]
  gemm256<true><<<dim3(12, 32, 1), dim3(512), 0, stream>>>(
      Qb, Wib, (void*)qkvb, 1024, 1024, 3072, 0, 0, 0, 1024, 1.0f);

  // 3) vT[b][e][t] from qkv v-part
  transpose_v<<<dim3(32, 16, 4), dim3(256), 0, stream>>>(qkvb, vT);

  // 4) scores[b] = (q/32) k^T -> bf16 directly into wbf (no fp32 round-trip)
  gemm256<true><<<dim3(8, 8, 4), dim3(512), 0, stream>>>(
      qkvb, qkvb + 1024, (void*)wbf, 12288, 12288, 2048,
      3072LL, 3072LL, 4194304LL, 1024, 0.03125f);

  // 5) softmax: bf16 scores -> fp32 weights (d_out) + bf16 probs in place
  softmax_rows<<<dim3(8192), dim3(256), 0, stream>>>(wbf, weights);

  // 6) att[t][b][e] = probs[b] * v[b]  (B = vT)
  gemm256<true><<<dim3(4, 8, 4), dim3(512), 0, stream>>>(
      wbf, vT, (void*)attb, 2048, 2048, 4096,
      4194304LL, 2097152LL, 1024LL, 2048, 1.0f);

  // 7) out = att * W_out^T -> fp32 d_out
  gemm256<false><<<dim3(4, 32, 1), dim3(512), 0, stream>>>(
      attb, Wob, (void*)out0, 1024, 1024, 1024, 0, 0, 0, 1024, 1.0f);
}